// Round 2
// baseline (251.619 us; speedup 1.0000x reference)
//
#include <hip/hip_runtime.h>
#include <stdint.h>

// PersonalMed: hierarchical GRU model on MI355X (gfx950).
// Dims: B=48, V=16, M=32, C=48, CM=8, D=128, VOCAB_V=2000, VOCAB_M=1000, OUT=256.
// ALL float inputs are float32 (verified via npz sizes); ids are int32.
// Output: [48][256] float32.
//
// Structure exploited:
//  - slots[1..3] are computed twice in the reference p-loop with identical
//    args -> compute once, scale by 2 in the final kernel.
//  - visit-feature monitor-GRU inputs are broadcast along M -> gi constant
//    over time (ts=0), input projection done once per row.
//  - GRU rows are independent -> block of 4 waves handles 16 rows for all
//    T steps; Whh frags live in VGPRs (each wave owns a 32-wide d-chunk of
//    all 3 gates = 6 MFMA N-tiles = 96 VGPRs); h ping-pongs through LDS.
//  - GRU weights pre-converted f32->bf16 once per call (k_prep) so MFMA
//    paths stay bf16; biases/activations math in f32.

typedef unsigned short u16;
typedef uint32_t u32;
typedef short bf8 __attribute__((ext_vector_type(8)));   // 8 bf16 = 4 VGPRs
typedef float f4 __attribute__((ext_vector_type(4)));

__device__ __forceinline__ float bf2f(u16 b){ u32 u = ((u32)b) << 16; float f; __builtin_memcpy(&f, &u, 4); return f; }
__device__ __forceinline__ u16 f2bf(float f){ u32 u; __builtin_memcpy(&u, &f, 4); u32 r = (u + 0x7fffu + ((u >> 16) & 1u)) >> 16; return (u16)r; }
__device__ __forceinline__ f4 mfma16(bf8 a, bf8 b, f4 c){ return __builtin_amdgcn_mfma_f32_16x16x32_bf16(a, b, c, 0, 0, 0); }
__device__ __forceinline__ float sigm(float x){ return 1.0f / (1.0f + __expf(-x)); }
__device__ __forceinline__ float tanh_f(float x){ return 1.0f - 2.0f / (__expf(2.0f * x) + 1.0f); }

// ---------------- weight f32->bf16 prep ----------------
// grid (336, 4), block 256, float4 granules.
__global__ __launch_bounds__(256) void k_prep(const float* __restrict__ s0, const float* __restrict__ s1,
                                              const float* __restrict__ s2, const float* __restrict__ s3,
                                              u16* __restrict__ d0, u16* __restrict__ d1,
                                              u16* __restrict__ d2, u16* __restrict__ d3){
  int y = blockIdx.y;
  const float* src = y == 0 ? s0 : y == 1 ? s1 : y == 2 ? s2 : s3;
  u16* dst         = y == 0 ? d0 : y == 1 ? d1 : y == 2 ? d2 : d3;
  int n4 = (y < 2 ? 245760 : 344064) >> 2;
  int i = blockIdx.x * 256 + threadIdx.x;
  if (i < n4){
    float4 v = *(const float4*)(src + i*4);
    ushort4 o = { f2bf(v.x), f2bf(v.y), f2bf(v.z), f2bf(v.w) };
    *(ushort4*)(dst + i*4) = o;
  }
}

// ---------------- embedding bags ----------------

// grid (768, 3), block 128. vis_org[k][bv][d] = sum_c emb_visit[k][id][d], id!=0
__global__ __launch_bounds__(128) void k_embed_visit(const int* __restrict__ vids,
                                                     const float* __restrict__ embv,
                                                     u16* __restrict__ vis_org){
  int k = blockIdx.y, bv = blockIdx.x, d = threadIdx.x;
  __shared__ int ids[48];
  if (d < 48) ids[d] = vids[((size_t)k*768 + bv)*48 + d];
  __syncthreads();
  const float* eb = embv + (size_t)k*2000*128;
  float acc = 0.f;
  #pragma unroll 4
  for (int c = 0; c < 48; ++c){ int id = ids[c]; if (id) acc += eb[(size_t)id*128 + d]; }
  vis_org[((size_t)k*768 + bv)*128 + d] = f2bf(acc);
}

// grid (24576, 2), block 128. mon_x[p][n*32+m][d] = sum_cm e1[id1][d]*e2[id2][d]
__global__ __launch_bounds__(128) void k_embed_mon(const int* __restrict__ mids,
                                                   const float* __restrict__ embm,
                                                   u16* __restrict__ mon_x){
  int p = blockIdx.y, d = threadIdx.x;
  size_t nm = blockIdx.x;
  __shared__ int ids[16];
  if (d < 16){ int f = 2*p + (d >> 3), cm = d & 7; ids[d] = mids[((size_t)f*24576 + nm)*8 + cm]; }
  __syncthreads();
  const float* e1 = embm + (size_t)(2*p)*1000*128;
  const float* e2 = embm + (size_t)(2*p+1)*1000*128;
  float acc = 0.f;
  #pragma unroll
  for (int c = 0; c < 8; ++c){
    int i1 = ids[c], i2 = ids[8+c];
    if (i1 && i2) acc += e1[(size_t)i1*128 + d] * e2[(size_t)i2*128 + d];
  }
  mon_x[((size_t)p*24576 + nm)*128 + d] = f2bf(acc);
}

// grid (768, 2), block 128. weight/age Linear(1->D) + zero-mask -> hin2 slots 5,6
__global__ __launch_bounds__(128) void k_wa(const float* __restrict__ wv, const float* __restrict__ av,
                                            const float* __restrict__ ww, const float* __restrict__ wb,
                                            const float* __restrict__ aw, const float* __restrict__ ab,
                                            u16* __restrict__ hin2){
  int s = blockIdx.y, row = blockIdx.x, d = threadIdx.x;
  const float* vals = s ? av : wv;
  const float* w    = s ? aw : ww;
  const float* bias = s ? ab : wb;
  float v = vals[row];
  float h = (v != 0.f) ? (v * w[d] + bias[d]) : 0.f;
  hin2[((size_t)(5+s)*768 + row)*128 + d] = f2bf(h);
}

// ---------------- input-projection GEMM ----------------
// OUT[r][384] = A[r][128] @ W[wi][384][128]^T + bias[wi][384], bf16 in/out, fp32 acc.
// grid (R/64, nStreams), block 256 (4 waves x 16 rows). wi = nibble of wsel.
__global__ __launch_bounds__(256) void k_proj(const u16* __restrict__ A, long long aY,
                                              const u16* __restrict__ W, const float* __restrict__ Bias,
                                              u16* __restrict__ OUT, long long oY, u32 wsel){
  int y = blockIdx.y;
  const u16* Ab = A + (size_t)y * aY;
  int wi = (wsel >> (4*y)) & 15;
  const u16* Wb = W + (size_t)wi*384*128;
  const float* bb = Bias + (size_t)wi*384;
  u16* Ob = OUT + (size_t)y * oY;
  int wave = threadIdx.x >> 6, l = threadIdx.x & 63;
  int lr = l & 15, lk = (l >> 4) * 8;
  int row0 = blockIdx.x*64 + wave*16;
  bf8 af[4];
  const u16* ap = Ab + (size_t)(row0 + lr)*128 + lk;
  #pragma unroll
  for (int kt = 0; kt < 4; ++kt) af[kt] = *(const bf8*)(ap + kt*32);
  for (int nt = 0; nt < 24; ++nt){
    const u16* wp = Wb + (size_t)(nt*16 + lr)*128 + lk;
    f4 acc = {0.f, 0.f, 0.f, 0.f};
    #pragma unroll
    for (int kt = 0; kt < 4; ++kt) acc = mfma16(af[kt], *(const bf8*)(wp + kt*32), acc);
    float bv = bb[nt*16 + lr];
    u16* op = Ob + (size_t)(row0 + (l >> 4)*4)*384 + nt*16 + lr;
    #pragma unroll
    for (int r = 0; r < 4; ++r) op[(size_t)r*384] = f2bf(acc[r] + bv);
  }
}

// ---------------- GRU recurrence ----------------
// mode 0 (monitor level): grid (48, 5), T=32.
//   s<2 : gi = giA[s] [768][32][384] (rs=32*384, ts=384)   [mon p-streams]
//   s>=2: gi = giB[s-2] [768][384]   (rs=384,    ts=0)     [broadcast streams]
//   Whh/bhh = mgru[s]; output -> hin2[slot], slot packed 0x32140.
// mode 1 (visit level): grid (3, 7), T=16.
//   gi = giA[s] [768][384], batch row b at b*16*384 (rs=16*384, ts=384)
//   Whh/bhh = vgru[vi], vi packed 0x6514320; output -> h2[s][48][128].
#define LOADGI(tt, dst) { \
  _Pragma("unroll") \
  for (int g = 0; g < 3; ++g){ \
    _Pragma("unroll") \
    for (int c = 0; c < 2; ++c){ \
      const u16* gp = gi + (size_t)(row0 + lkg*4)*rs + (size_t)(tt)*ts + (g*128 + wave*32 + c*16 + lr); \
      _Pragma("unroll") \
      for (int r = 0; r < 4; ++r) dst[g*2+c][r] = bf2f(gp[(size_t)r*rs]); \
    } \
  } }

__global__ __launch_bounds__(256, 1) void k_gru(int mode,
    const u16* __restrict__ giA, const u16* __restrict__ giB,
    const u16* __restrict__ Whh, const float* __restrict__ bhh,
    u16* __restrict__ hout, int T){
  int s = blockIdx.y;
  const u16* gi; int rs, ts; const u16* Wb; const float* bh; u16* ho;
  if (mode == 0){
    if (s < 2){ gi = giA + (size_t)s*768*32*384; rs = 32*384; ts = 384; }
    else      { gi = giB + (size_t)(s-2)*768*384; rs = 384; ts = 0; }
    Wb = Whh + (size_t)s*384*128; bh = bhh + (size_t)s*384;
    int slot = (0x32140u >> (4*s)) & 15;
    ho = hout + (size_t)slot*768*128;
  } else {
    gi = giA + (size_t)s*768*384; rs = 16*384; ts = 384;
    int vi = (0x6514320u >> (4*s)) & 15;
    Wb = Whh + (size_t)vi*384*128; bh = bhh + (size_t)vi*384;
    ho = hout + (size_t)s*48*128;
  }
  int wave = threadIdx.x >> 6, l = threadIdx.x & 63;
  int lr = l & 15, lkg = l >> 4;
  int row0 = blockIdx.x * 16;

  // Whh fragments: wave owns d-chunk [32*wave, 32*wave+32) of all 3 gates.
  bf8 wfrag[6][4];
  float bhv[6];
  #pragma unroll
  for (int g = 0; g < 3; ++g)
    #pragma unroll
    for (int c = 0; c < 2; ++c){
      int colb = g*128 + wave*32 + c*16;
      const u16* wp = Wb + (size_t)(colb + lr)*128 + lkg*8;
      #pragma unroll
      for (int kt = 0; kt < 4; ++kt) wfrag[g*2+c][kt] = *(const bf8*)(wp + kt*32);
      bhv[g*2+c] = bh[colb + lr];
    }

  __shared__ u16 hlds[2][16][136];   // +8 u16 pad -> breaks bank conflicts
  for (int i = threadIdx.x; i < 16*136; i += 256) ((u16*)hlds)[i] = 0;
  __syncthreads();

  float hprev[2][4] = {{0.f,0.f,0.f,0.f},{0.f,0.f,0.f,0.f}};
  float gcur[6][4], gnext[6][4];
  LOADGI(0, gcur);

  int cur = 0;
  for (int t = 0; t < T; ++t){
    if (ts && t+1 < T) LOADGI(t+1, gnext);
    bf8 hf[4];
    #pragma unroll
    for (int kt = 0; kt < 4; ++kt)
      hf[kt] = *(const bf8*)&hlds[cur][lr][kt*32 + lkg*8];
    f4 acc[6];
    #pragma unroll
    for (int i = 0; i < 6; ++i){ f4 t4 = {bhv[i], bhv[i], bhv[i], bhv[i]}; acc[i] = t4; }
    #pragma unroll
    for (int i = 0; i < 6; ++i)
      #pragma unroll
      for (int kt = 0; kt < 4; ++kt) acc[i] = mfma16(hf[kt], wfrag[i][kt], acc[i]);
    int nxt = cur ^ 1;
    #pragma unroll
    for (int c = 0; c < 2; ++c)
      #pragma unroll
      for (int r = 0; r < 4; ++r){
        float rr = sigm(gcur[c][r]     + acc[c][r]);
        float zz = sigm(gcur[2+c][r]   + acc[2+c][r]);
        float nn = tanh_f(gcur[4+c][r] + rr * acc[4+c][r]);
        float hv = (1.0f - zz)*nn + zz*hprev[c][r];
        hprev[c][r] = hv;
        hlds[nxt][lkg*4 + r][wave*32 + c*16 + lr] = f2bf(hv);
      }
    __syncthreads();
    cur = nxt;
    if (ts && t+1 < T){
      #pragma unroll
      for (int i = 0; i < 6; ++i)
        #pragma unroll
        for (int r = 0; r < 4; ++r) gcur[i][r] = gnext[i][r];
    }
  }
  #pragma unroll
  for (int c = 0; c < 2; ++c)
    #pragma unroll
    for (int r = 0; r < 4; ++r)
      ho[(size_t)(row0 + lkg*4 + r)*128 + wave*32 + c*16 + lr] = f2bf(hprev[c][r]);
}

// ---------------- final projection ----------------
// grid 48, block 256. out[b][o] = relu-concat(slots) @ fc_out_w^T + fc_out_b
__global__ __launch_bounds__(256) void k_final(const u16* __restrict__ h2,
                                               const float* __restrict__ W,
                                               const float* __restrict__ Bias,
                                               float* __restrict__ out){
  int b = blockIdx.x, t = threadIdx.x;
  __shared__ float emb[896];
  for (int i = t; i < 896; i += 256){
    int j = i >> 7, d = i & 127;
    float v = bf2f(h2[((size_t)j*48 + b)*128 + d]);
    if (j >= 1 && j <= 3) v *= 2.0f;   // slots 1..3 summed twice in reference
    emb[i] = fmaxf(v, 0.f);
  }
  __syncthreads();
  float acc = Bias[t];
  const float* wp = W + (size_t)t*896;
  for (int i = 0; i < 896; i += 8){
    float4 w0 = *(const float4*)(wp + i);
    float4 w1 = *(const float4*)(wp + i + 4);
    acc += w0.x*emb[i]   + w0.y*emb[i+1] + w0.z*emb[i+2] + w0.w*emb[i+3];
    acc += w1.x*emb[i+4] + w1.y*emb[i+5] + w1.z*emb[i+6] + w1.w*emb[i+7];
  }
  out[(size_t)b*256 + t] = acc;
}

extern "C" void kernel_launch(void* const* d_in, const int* in_sizes, int n_in,
                              void* d_out, int out_size, void* d_ws, size_t ws_size,
                              hipStream_t stream){
  const int*   visit_ids   = (const int*)d_in[0];
  const int*   mon_ids     = (const int*)d_in[1];
  const float* weight_vals = (const float*)d_in[2];
  const float* age_vals    = (const float*)d_in[3];
  const float* emb_visit   = (const float*)d_in[4];
  const float* emb_mon     = (const float*)d_in[5];
  const float* mgru_Wih    = (const float*)d_in[6];
  const float* mgru_Whh    = (const float*)d_in[7];
  const float* mgru_bih    = (const float*)d_in[8];
  const float* mgru_bhh    = (const float*)d_in[9];
  const float* vgru_Wih    = (const float*)d_in[10];
  const float* vgru_Whh    = (const float*)d_in[11];
  const float* vgru_bih    = (const float*)d_in[12];
  const float* vgru_bhh    = (const float*)d_in[13];
  const float* fc_w_w      = (const float*)d_in[14];
  const float* fc_w_b      = (const float*)d_in[15];
  const float* fc_a_w      = (const float*)d_in[16];
  const float* fc_a_b      = (const float*)d_in[17];
  const float* fc_out_w    = (const float*)d_in[18];
  const float* fc_out_b    = (const float*)d_in[19];

  char* ws = (char*)d_ws;
  size_t o = 0;
  u16* mWih_b  = (u16*)(ws + o); o += 5ull*384*128*2;     // bf16 weights (k_prep)
  u16* mWhh_b  = (u16*)(ws + o); o += 5ull*384*128*2;
  u16* vWih_b  = (u16*)(ws + o); o += 7ull*384*128*2;
  u16* vWhh_b  = (u16*)(ws + o); o += 7ull*384*128*2;
  u16* mon_x   = (u16*)(ws + o); o += 2ull*24576*128*2;   // 12.6 MB
  u16* gi_mon  = (u16*)(ws + o); o += 2ull*24576*384*2;   // 37.7 MB
  u16* vis_org = (u16*)(ws + o); o += 3ull*768*128*2;
  u16* xi_c    = (u16*)(ws + o); o += 3ull*768*384*2;
  u16* hin2    = (u16*)(ws + o); o += 7ull*768*128*2;     // slot-ordered GRU-2 inputs
  u16* xi2     = (u16*)(ws + o); o += 7ull*768*384*2;
  u16* h2      = (u16*)(ws + o); o += 7ull*48*128*2;      // total ~61 MB

  k_prep<<<dim3(336,4), 256, 0, stream>>>(mgru_Wih, mgru_Whh, vgru_Wih, vgru_Whh,
                                          mWih_b, mWhh_b, vWih_b, vWhh_b);
  k_embed_visit<<<dim3(768,3),   128, 0, stream>>>(visit_ids, emb_visit, vis_org);
  k_embed_mon  <<<dim3(24576,2), 128, 0, stream>>>(mon_ids, emb_mon, mon_x);
  k_wa         <<<dim3(768,2),   128, 0, stream>>>(weight_vals, age_vals, fc_w_w, fc_w_b, fc_a_w, fc_a_b, hin2);
  // gi for mon p-streams: [24576,128]@[384,128]^T per p
  k_proj<<<dim3(384,2), 256, 0, stream>>>(mon_x, 24576LL*128, mWih_b, mgru_bih, gi_mon, 24576LL*384, 0x10u);
  // constant gi for broadcast streams (mgru idx 2..4)
  k_proj<<<dim3(12,3), 256, 0, stream>>>(vis_org, 768LL*128, mWih_b, mgru_bih, xi_c, 768LL*384, 0x432u);
  // monitor-level GRU: 5 streams x 768 rows x T=32 -> hin2 slots {0,4,1,2,3}
  k_gru<<<dim3(48,5), 256, 0, stream>>>(0, gi_mon, xi_c, mWhh_b, mgru_bhh, hin2, 32);
  // visit-level input projections: 7 streams, vgru idx {0,2,3,4,1,5,6}
  k_proj<<<dim3(12,7), 256, 0, stream>>>(hin2, 768LL*128, vWih_b, vgru_bih, xi2, 768LL*384, 0x6514320u);
  // visit-level GRU: 7 streams x 48 rows x T=16 -> h2
  k_gru<<<dim3(3,7), 256, 0, stream>>>(1, xi2, (const u16*)0, vWhh_b, vgru_bhh, h2, 16);
  k_final<<<48, 256, 0, stream>>>(h2, fc_out_w, fc_out_b, (float*)d_out);
}

// Round 3
// 210.311 us; speedup vs baseline: 1.1964x; 1.1964x over previous
//
#include <hip/hip_runtime.h>
#include <stdint.h>

// PersonalMed on MI355X. B=48,V=16,M=32,C=48,CM=8,D=128,OUT=256. f32 in/out.
// Round-3 structure:
//  - gi tensors stored FRAGMENT-MAJOR: [group][tile nt<24][lane<64][2 u32]
//    (u32 = bf16 pair of C-rows 2w,2w+1). Producer (k_proj) lane == consumer
//    (k_gru) lane, so GRU reads 6 coalesced dwords/step instead of 24 scalars.
//  - mon_x transposed to [m][bv] and hin2 to [v][b] so every projection's
//    16-row MFMA tile == one GRU group (16 parallel rows at one time step).
//  - k_gru: 512 thr = 8 waves, each wave owns a 16-wide d-chunk (tiles
//    {w, 8+w, 16+w}); 12 MFMA/step/wave; h ping-pongs via LDS, one barrier
//    per step; gi prefetched through a depth-4 register ring.

typedef unsigned short u16;
typedef uint32_t u32;
typedef short bf8 __attribute__((ext_vector_type(8)));   // 8 bf16 = 4 VGPRs
typedef float f4 __attribute__((ext_vector_type(4)));

static __device__ __forceinline__ float bf2f(u16 b){ u32 u=((u32)b)<<16; float f; __builtin_memcpy(&f,&u,4); return f; }
static __device__ __forceinline__ u16 f2bf(float f){ u32 u; __builtin_memcpy(&u,&f,4); u32 r=(u+0x7fffu+((u>>16)&1u))>>16; return (u16)r; }
static __device__ __forceinline__ float bflo(u32 u){ u32 x=u<<16; float f; __builtin_memcpy(&f,&x,4); return f; }
static __device__ __forceinline__ float bfhi(u32 u){ u32 x=u&0xffff0000u; float f; __builtin_memcpy(&f,&x,4); return f; }
static __device__ __forceinline__ f4 mfma16(bf8 a, bf8 b, f4 c){ return __builtin_amdgcn_mfma_f32_16x16x32_bf16(a,b,c,0,0,0); }
static __device__ __forceinline__ float sigm(float x){ return 1.0f/(1.0f+__expf(-x)); }
static __device__ __forceinline__ float tanh_f(float x){ return 1.0f-2.0f/(__expf(2.0f*x)+1.0f); }

// ---------------- f32->bf16 prep (GRU weights + emb_mon tables) ----------------
// grid (500,5), block 256.
__global__ __launch_bounds__(256) void k_prep(const float* __restrict__ s0, const float* __restrict__ s1,
                                              const float* __restrict__ s2, const float* __restrict__ s3,
                                              const float* __restrict__ s4,
                                              u16* __restrict__ d0, u16* __restrict__ d1,
                                              u16* __restrict__ d2, u16* __restrict__ d3,
                                              u16* __restrict__ d4){
  int y = blockIdx.y;
  const float* src = y==0?s0 : y==1?s1 : y==2?s2 : y==3?s3 : s4;
  u16* dst         = y==0?d0 : y==1?d1 : y==2?d2 : y==3?d3 : d4;
  int n4 = (y<2 ? 245760 : y<4 ? 344064 : 512000) >> 2;
  int i = blockIdx.x*256 + threadIdx.x;
  if (i < n4){
    float4 v = *(const float4*)(src + (size_t)i*4);
    ushort4 o = { f2bf(v.x), f2bf(v.y), f2bf(v.z), f2bf(v.w) };
    *(ushort4*)(dst + (size_t)i*4) = o;
  }
}

// ---------------- embedding bags ----------------
// grid (768,3), block 128. vis_org[k][bv][d] = sum_c emb_visit[k][id][d], id!=0
__global__ __launch_bounds__(128) void k_embed_visit(const int* __restrict__ vids,
                                                     const float* __restrict__ embv,
                                                     u16* __restrict__ vis_org){
  int k = blockIdx.y, bv = blockIdx.x, d = threadIdx.x;
  __shared__ int ids[48];
  if (d < 48) ids[d] = vids[((size_t)k*768 + bv)*48 + d];
  __syncthreads();
  const float* eb = embv + (size_t)k*2000*128;
  float acc = 0.f;
  #pragma unroll 4
  for (int c = 0; c < 48; ++c){ int id = ids[c]; if (id) acc += eb[(size_t)id*128 + d]; }
  vis_org[((size_t)k*768 + bv)*128 + d] = f2bf(acc);
}

// grid (3072,2), block 256: 8 rows/block, 32 lanes/row, 4 d/lane (8B gathers).
// mon_xT[p][m*768+bv][d] = sum_cm e1[id1][d]*e2[id2][d]  (bf16 tables)
__global__ __launch_bounds__(256) void k_embed_mon(const int* __restrict__ mids,
                                                   const u16* __restrict__ embm_b,
                                                   u16* __restrict__ mon_xT){
  int p = blockIdx.y;
  int rid = threadIdx.x >> 5, lane32 = threadIdx.x & 31, d0 = lane32*4;
  __shared__ int ids[8][16];
  if (threadIdx.x < 128){
    int rr = threadIdx.x >> 4, c = threadIdx.x & 15;
    int f = 2*p + (c>>3), cm = c & 7;
    ids[rr][c] = mids[((size_t)f*24576 + (size_t)blockIdx.x*8 + rr)*8 + cm];
  }
  __syncthreads();
  const u16* e1 = embm_b + (size_t)(2*p)*1000*128;
  const u16* e2 = embm_b + (size_t)(2*p+1)*1000*128;
  float a0=0.f,a1=0.f,a2=0.f,a3=0.f;
  #pragma unroll
  for (int c = 0; c < 8; ++c){
    int i1 = ids[rid][c], i2 = ids[rid][8+c];
    if (i1 && i2){
      uint2 a = *(const uint2*)(e1 + (size_t)i1*128 + d0);
      uint2 b = *(const uint2*)(e2 + (size_t)i2*128 + d0);
      a0 += bflo(a.x)*bflo(b.x); a1 += bfhi(a.x)*bfhi(b.x);
      a2 += bflo(a.y)*bflo(b.y); a3 += bfhi(a.y)*bfhi(b.y);
    }
  }
  size_t nm = (size_t)blockIdx.x*8 + rid;
  int bv = (int)(nm >> 5), m = (int)(nm & 31);
  ushort4 o = { f2bf(a0), f2bf(a1), f2bf(a2), f2bf(a3) };
  *(ushort4*)(mon_xT + (size_t)p*24576*128 + ((size_t)m*768 + bv)*128 + d0) = o;
}

// grid (768,2), block 128. weight/age Linear(1->D)+mask -> hin2T slots 5,6 ([v][b] layout)
__global__ __launch_bounds__(128) void k_wa(const float* __restrict__ wv, const float* __restrict__ av,
                                            const float* __restrict__ ww, const float* __restrict__ wb,
                                            const float* __restrict__ aw, const float* __restrict__ ab,
                                            u16* __restrict__ hin2T){
  int s = blockIdx.y, row = blockIdx.x, d = threadIdx.x;
  const float* vals = s ? av : wv;
  const float* w    = s ? aw : ww;
  const float* bias = s ? ab : wb;
  float v = vals[row];
  float h = (v != 0.f) ? (v * w[d] + bias[d]) : 0.f;
  int b = row >> 4, vv = row & 15;
  hin2T[((size_t)(5+s)*768 + (size_t)vv*48 + b)*128 + d] = f2bf(h);
}

// ---------------- input projections (frag-major output) ----------------
// merged stage-1: grid (384,5) block 256.
//  y<2 : gi_mon p=y from mon_xT; y>=2 (x<12): xi_c k=y-2 from vis_org.
__global__ __launch_bounds__(256) void k_proj_m(const u16* __restrict__ mon_xT,
                                                const u16* __restrict__ vis_org,
                                                const u16* __restrict__ Wih,
                                                const float* __restrict__ bih,
                                                u32* __restrict__ gmf, u32* __restrict__ xcf){
  int y = blockIdx.y;
  const u16* Ab; const u16* Wb; const float* bb; u32* Of;
  if (y < 2){
    Ab = mon_xT + (size_t)y*24576*128; Wb = Wih + (size_t)y*384*128;
    bb = bih + (size_t)y*384;          Of = gmf + (size_t)y*1536*3072;
  } else {
    if (blockIdx.x >= 12) return;
    int k = y-2;
    Ab = vis_org + (size_t)k*768*128;  Wb = Wih + (size_t)(2+k)*384*128;
    bb = bih + (size_t)(2+k)*384;      Of = xcf + (size_t)k*48*3072;
  }
  int wave = threadIdx.x >> 6, l = threadIdx.x & 63;
  int lr = l & 15, lq = l >> 4;
  int row0 = blockIdx.x*64 + wave*16;
  bf8 af[4];
  const u16* ap = Ab + (size_t)(row0 + lr)*128 + lq*8;
  #pragma unroll
  for (int kt = 0; kt < 4; ++kt) af[kt] = *(const bf8*)(ap + kt*32);
  u32* ob = Of + (size_t)(row0 >> 4)*24*128 + l*2;
  for (int nt = 0; nt < 24; ++nt){
    const u16* wp = Wb + (size_t)(nt*16 + lr)*128 + lq*8;
    f4 acc = {0.f,0.f,0.f,0.f};
    #pragma unroll
    for (int kt = 0; kt < 4; ++kt) acc = mfma16(af[kt], *(const bf8*)(wp + kt*32), acc);
    float bv = bb[nt*16 + lr];
    uint2 ww;
    ww.x = (u32)f2bf(acc[0]+bv) | ((u32)f2bf(acc[1]+bv) << 16);
    ww.y = (u32)f2bf(acc[2]+bv) | ((u32)f2bf(acc[3]+bv) << 16);
    *(uint2*)(ob + (size_t)nt*128) = ww;
  }
}

// stage-2 (xi2): grid (12,7) block 256. A = hin2T[s] rows v*48+b.
__global__ __launch_bounds__(256) void k_proj(const u16* __restrict__ A, long long aY,
                                              const u16* __restrict__ W, const float* __restrict__ Bias,
                                              u32* __restrict__ OF, long long oY, u32 wsel){
  int y = blockIdx.y;
  const u16* Ab = A + (size_t)y*aY;
  int wi = (wsel >> (4*y)) & 15;
  const u16* Wb = W + (size_t)wi*384*128;
  const float* bb = Bias + (size_t)wi*384;
  u32* Of = OF + (size_t)y*oY;
  int wave = threadIdx.x >> 6, l = threadIdx.x & 63;
  int lr = l & 15, lq = l >> 4;
  int row0 = blockIdx.x*64 + wave*16;
  bf8 af[4];
  const u16* ap = Ab + (size_t)(row0 + lr)*128 + lq*8;
  #pragma unroll
  for (int kt = 0; kt < 4; ++kt) af[kt] = *(const bf8*)(ap + kt*32);
  u32* ob = Of + (size_t)(row0 >> 4)*24*128 + l*2;
  for (int nt = 0; nt < 24; ++nt){
    const u16* wp = Wb + (size_t)(nt*16 + lr)*128 + lq*8;
    f4 acc = {0.f,0.f,0.f,0.f};
    #pragma unroll
    for (int kt = 0; kt < 4; ++kt) acc = mfma16(af[kt], *(const bf8*)(wp + kt*32), acc);
    float bv = bb[nt*16 + lr];
    uint2 ww;
    ww.x = (u32)f2bf(acc[0]+bv) | ((u32)f2bf(acc[1]+bv) << 16);
    ww.y = (u32)f2bf(acc[2]+bv) | ((u32)f2bf(acc[3]+bv) << 16);
    *(uint2*)(ob + (size_t)nt*128) = ww;
  }
}

// ---------------- GRU recurrence (8-wave, frag gi, depth-4 prefetch) ----------------
// mode 0: grid (48,5) T=32. s<2: gi=gim_f[s], gstep=48. s>=2: gi=xic_f[s-2], gstep=0.
//         weights mgru[s]; out hin2T[slot], slot=0x32140 nibble; store [v=rr][b=g].
// mode 1: grid (3,7) T=16. gi=xi2_f[s], gstep=3; weights vgru[vi], vi=0x6514320
//         nibble; out h2[s] row-major [b][128], b=g*16+rr.
#define GLOAD(D, tt) { const u32* gp = gpw + (size_t)(tt)*gstride; \
    D[0]=gp[0]; D[1]=gp[1]; D[2]=gp[1024]; D[3]=gp[1025]; D[4]=gp[2048]; D[5]=gp[2049]; }

#define STEP(D, tt, FIRST) { \
  f4 acc0 = {bhv[0],bhv[0],bhv[0],bhv[0]}; \
  f4 acc1 = {bhv[1],bhv[1],bhv[1],bhv[1]}; \
  f4 acc2 = {bhv[2],bhv[2],bhv[2],bhv[2]}; \
  if (!(FIRST)){ \
    bf8 hf0 = *(const bf8*)&hlds[cur][lr][0*32+lq*8]; \
    bf8 hf1 = *(const bf8*)&hlds[cur][lr][1*32+lq*8]; \
    bf8 hf2 = *(const bf8*)&hlds[cur][lr][2*32+lq*8]; \
    bf8 hf3 = *(const bf8*)&hlds[cur][lr][3*32+lq*8]; \
    acc0=mfma16(hf0,wfrag[0][0],acc0); acc0=mfma16(hf1,wfrag[0][1],acc0); \
    acc0=mfma16(hf2,wfrag[0][2],acc0); acc0=mfma16(hf3,wfrag[0][3],acc0); \
    acc1=mfma16(hf0,wfrag[1][0],acc1); acc1=mfma16(hf1,wfrag[1][1],acc1); \
    acc1=mfma16(hf2,wfrag[1][2],acc1); acc1=mfma16(hf3,wfrag[1][3],acc1); \
    acc2=mfma16(hf0,wfrag[2][0],acc2); acc2=mfma16(hf1,wfrag[2][1],acc2); \
    acc2=mfma16(hf2,wfrag[2][2],acc2); acc2=mfma16(hf3,wfrag[2][3],acc2); \
  } \
  int nxt2 = cur ^ 1; \
  _Pragma("unroll") \
  for (int r = 0; r < 4; ++r){ \
    float gr = (r&1) ? bfhi(D[(r>>1)])   : bflo(D[(r>>1)]); \
    float gz = (r&1) ? bfhi(D[2+(r>>1)]) : bflo(D[2+(r>>1)]); \
    float gn = (r&1) ? bfhi(D[4+(r>>1)]) : bflo(D[4+(r>>1)]); \
    float rr2 = sigm(gr + acc0[r]); \
    float zz  = sigm(gz + acc1[r]); \
    float nn  = tanh_f(gn + rr2*acc2[r]); \
    float hv  = (1.0f - zz)*nn + zz*hp[r]; hp[r] = hv; \
    hlds[nxt2][lq*4+r][w*16+lr] = f2bf(hv); \
  } \
  { int tl = ((tt)+4 < T) ? (tt)+4 : 0; GLOAD(D, tl); } \
  __syncthreads(); cur = nxt2; }

__global__ __launch_bounds__(512, 1) void k_gru(int mode,
    const u32* __restrict__ giA, const u32* __restrict__ giB,
    const u16* __restrict__ Whh, const float* __restrict__ bhh,
    u16* __restrict__ hout, int T){
  int s = blockIdx.y, g = blockIdx.x;
  const u32* gf; int gstep; const u16* Wb; const float* bh; u16* ho;
  if (mode == 0){
    if (s < 2){ gf = giA + (size_t)s*1536*3072; gstep = 48; }
    else      { gf = giB + (size_t)(s-2)*48*3072; gstep = 0; }
    Wb = Whh + (size_t)s*384*128; bh = bhh + (size_t)s*384;
    int slot = (0x32140u >> (4*s)) & 15;
    ho = hout + (size_t)slot*768*128;
  } else {
    gf = giA + (size_t)s*16*3*3072; gstep = 3;
    int vi = (0x6514320u >> (4*s)) & 15;
    Wb = Whh + (size_t)vi*384*128; bh = bhh + (size_t)vi*384;
    ho = hout + (size_t)s*48*128;
  }
  int w = threadIdx.x >> 6, l = threadIdx.x & 63;
  int lr = l & 15, lq = l >> 4;
  size_t gstride = (size_t)gstep * 3072;

  // weight frags: wave w owns tiles {w, 8+w, 16+w} (r,z,n gate col-chunk w*16..+16)
  bf8 wfrag[3][4]; float bhv[3];
  #pragma unroll
  for (int j = 0; j < 3; ++j){
    int colb = (w + 8*j)*16;
    const u16* wp = Wb + (size_t)(colb + lr)*128 + lq*8;
    #pragma unroll
    for (int kt = 0; kt < 4; ++kt) wfrag[j][kt] = *(const bf8*)(wp + kt*32);
    bhv[j] = bh[colb + lr];
  }

  const u32* gpw = gf + (size_t)g*3072 + w*128 + l*2;
  u32 G0[6], G1[6], G2[6], G3[6];
  GLOAD(G0, 0); GLOAD(G1, 1); GLOAD(G2, 2); GLOAD(G3, 3);

  __shared__ u16 hlds[2][16][136];
  float hp[4] = {0.f,0.f,0.f,0.f};
  int cur = 0;

  STEP(G0, 0, true);
  STEP(G1, 1, false); STEP(G2, 2, false); STEP(G3, 3, false);
  for (int t = 4; t < T; t += 4){
    STEP(G0, t,   false); STEP(G1, t+1, false);
    STEP(G2, t+2, false); STEP(G3, t+3, false);
  }

  if (mode == 0){
    #pragma unroll
    for (int r = 0; r < 4; ++r)
      ho[((size_t)(lq*4+r)*48 + g)*128 + w*16 + lr] = f2bf(hp[r]);
  } else {
    #pragma unroll
    for (int r = 0; r < 4; ++r)
      ho[((size_t)(g*16 + lq*4 + r))*128 + w*16 + lr] = f2bf(hp[r]);
  }
}

// ---------------- final projection ----------------
__global__ __launch_bounds__(256) void k_final(const u16* __restrict__ h2,
                                               const float* __restrict__ W,
                                               const float* __restrict__ Bias,
                                               float* __restrict__ out){
  int b = blockIdx.x, t = threadIdx.x;
  __shared__ float emb[896];
  for (int i = t; i < 896; i += 256){
    int j = i >> 7, d = i & 127;
    float v = bf2f(h2[((size_t)j*48 + b)*128 + d]);
    if (j >= 1 && j <= 3) v *= 2.0f;   // slots 1..3 appear twice in reference sum
    emb[i] = fmaxf(v, 0.f);
  }
  __syncthreads();
  float acc = Bias[t];
  const float* wp = W + (size_t)t*896;
  for (int i = 0; i < 896; i += 8){
    float4 w0 = *(const float4*)(wp + i);
    float4 w1 = *(const float4*)(wp + i + 4);
    acc += w0.x*emb[i]   + w0.y*emb[i+1] + w0.z*emb[i+2] + w0.w*emb[i+3];
    acc += w1.x*emb[i+4] + w1.y*emb[i+5] + w1.z*emb[i+6] + w1.w*emb[i+7];
  }
  out[(size_t)b*256 + t] = acc;
}

extern "C" void kernel_launch(void* const* d_in, const int* in_sizes, int n_in,
                              void* d_out, int out_size, void* d_ws, size_t ws_size,
                              hipStream_t stream){
  const int*   visit_ids   = (const int*)d_in[0];
  const int*   mon_ids     = (const int*)d_in[1];
  const float* weight_vals = (const float*)d_in[2];
  const float* age_vals    = (const float*)d_in[3];
  const float* emb_visit   = (const float*)d_in[4];
  const float* emb_mon     = (const float*)d_in[5];
  const float* mgru_Wih    = (const float*)d_in[6];
  const float* mgru_Whh    = (const float*)d_in[7];
  const float* mgru_bih    = (const float*)d_in[8];
  const float* mgru_bhh    = (const float*)d_in[9];
  const float* vgru_Wih    = (const float*)d_in[10];
  const float* vgru_Whh    = (const float*)d_in[11];
  const float* vgru_bih    = (const float*)d_in[12];
  const float* vgru_bhh    = (const float*)d_in[13];
  const float* fc_w_w      = (const float*)d_in[14];
  const float* fc_w_b      = (const float*)d_in[15];
  const float* fc_a_w      = (const float*)d_in[16];
  const float* fc_a_b      = (const float*)d_in[17];
  const float* fc_out_w    = (const float*)d_in[18];
  const float* fc_out_b    = (const float*)d_in[19];

  char* ws = (char*)d_ws;
  size_t o = 0;
  u16* mWih_b  = (u16*)(ws+o); o += 5ull*384*128*2;
  u16* mWhh_b  = (u16*)(ws+o); o += 5ull*384*128*2;
  u16* vWih_b  = (u16*)(ws+o); o += 7ull*384*128*2;
  u16* vWhh_b  = (u16*)(ws+o); o += 7ull*384*128*2;
  u16* embm_b  = (u16*)(ws+o); o += 4ull*1000*128*2;
  u16* mon_xT  = (u16*)(ws+o); o += 2ull*24576*128*2;    // [p][m*768+bv][128]
  u32* gim_f   = (u32*)(ws+o); o += 2ull*1536*3072*4;    // frag gi, monitor p-streams
  u16* vis_org = (u16*)(ws+o); o += 3ull*768*128*2;
  u32* xic_f   = (u32*)(ws+o); o += 3ull*48*3072*4;      // frag gi, broadcast streams
  u16* hin2T   = (u16*)(ws+o); o += 7ull*768*128*2;      // [slot][v*48+b][128]
  u32* xi2_f   = (u32*)(ws+o); o += 7ull*48*3072*4;      // frag gi, visit streams
  u16* h2      = (u16*)(ws+o); o += 7ull*48*128*2;       // ~61.6 MB total

  k_prep<<<dim3(500,5), 256, 0, stream>>>(mgru_Wih, mgru_Whh, vgru_Wih, vgru_Whh, emb_mon,
                                          mWih_b, mWhh_b, vWih_b, vWhh_b, embm_b);
  k_embed_visit<<<dim3(768,3), 128, 0, stream>>>(visit_ids, emb_visit, vis_org);
  k_embed_mon  <<<dim3(3072,2), 256, 0, stream>>>(mon_ids, embm_b, mon_xT);
  k_wa         <<<dim3(768,2), 128, 0, stream>>>(weight_vals, age_vals, fc_w_w, fc_w_b, fc_a_w, fc_a_b, hin2T);
  k_proj_m<<<dim3(384,5), 256, 0, stream>>>(mon_xT, vis_org, mWih_b, mgru_bih, gim_f, xic_f);
  k_gru<<<dim3(48,5), 512, 0, stream>>>(0, gim_f, xic_f, mWhh_b, mgru_bhh, hin2T, 32);
  k_proj<<<dim3(12,7), 256, 0, stream>>>(hin2T, 768LL*128, vWih_b, vgru_bih, xi2_f, 48LL*3072, 0x6514320u);
  k_gru<<<dim3(3,7), 512, 0, stream>>>(1, xi2_f, (const u32*)0, vWhh_b, vgru_bhh, h2, 16);
  k_final<<<48, 256, 0, stream>>>(h2, fc_out_w, fc_out_b, (float*)d_out);
}

// Round 4
// 141.166 us; speedup vs baseline: 1.7824x; 1.4898x over previous
//
#include <hip/hip_runtime.h>
#include <stdint.h>

// PersonalMed on MI355X. B=48,V=16,M=32,C=48,CM=8,D=128,OUT=256. f32 in/out.
// Round-4: input projection FUSED into the GRU. Each k_gru wave holds both
// Wih and Whh fragments (3 gate-tiles x 4 k-frags each) in VGPRs and computes
// gi = x@Wih^T + bih per step (12 independent MFMAs) + gh = h@Whh^T + bhh
// (12 MFMAs on the recurrence chain). x-fragments stream through a depth-2
// register ring prefetched 2 steps ahead. No gi tensors in memory at all.
//  - group g == batch row b; within-group row == v (or m-step row). A-rows
//    for a group are 16 contiguous rows of the source tensor at each step.
//  - hlds stride 132 u16 (66 dwords == 2 mod 32) -> conflict-free b128 reads.
//  - slots 1..3 identical across the reference's p-loop -> computed once,
//    doubled in k_final.

typedef unsigned short u16;
typedef uint32_t u32;
typedef short bf8 __attribute__((ext_vector_type(8)));   // 8 bf16 = 4 VGPRs
typedef float f4 __attribute__((ext_vector_type(4)));

static __device__ __forceinline__ float bf2f(u16 b){ u32 u=((u32)b)<<16; float f; __builtin_memcpy(&f,&u,4); return f; }
static __device__ __forceinline__ u16 f2bf(float f){ u32 u; __builtin_memcpy(&u,&f,4); u32 r=(u+0x7fffu+((u>>16)&1u))>>16; return (u16)r; }
static __device__ __forceinline__ float bflo(u32 u){ u32 x=u<<16; float f; __builtin_memcpy(&f,&x,4); return f; }
static __device__ __forceinline__ float bfhi(u32 u){ u32 x=u&0xffff0000u; float f; __builtin_memcpy(&f,&x,4); return f; }
static __device__ __forceinline__ f4 mfma16(bf8 a, bf8 b, f4 c){ return __builtin_amdgcn_mfma_f32_16x16x32_bf16(a,b,c,0,0,0); }
static __device__ __forceinline__ float sigm(float x){ return 1.0f/(1.0f+__expf(-x)); }
static __device__ __forceinline__ float tanh_f(float x){ return 1.0f-2.0f/(__expf(2.0f*x)+1.0f); }

// ---------------- f32->bf16 prep (GRU weights + emb_mon tables) ----------------
// grid (500,5), block 256.
__global__ __launch_bounds__(256) void k_prep(const float* __restrict__ s0, const float* __restrict__ s1,
                                              const float* __restrict__ s2, const float* __restrict__ s3,
                                              const float* __restrict__ s4,
                                              u16* __restrict__ d0, u16* __restrict__ d1,
                                              u16* __restrict__ d2, u16* __restrict__ d3,
                                              u16* __restrict__ d4){
  int y = blockIdx.y;
  const float* src = y==0?s0 : y==1?s1 : y==2?s2 : y==3?s3 : s4;
  u16* dst         = y==0?d0 : y==1?d1 : y==2?d2 : y==3?d3 : d4;
  int n4 = (y<2 ? 245760 : y<4 ? 344064 : 512000) >> 2;
  int i = blockIdx.x*256 + threadIdx.x;
  if (i < n4){
    float4 v = *(const float4*)(src + (size_t)i*4);
    ushort4 o = { f2bf(v.x), f2bf(v.y), f2bf(v.z), f2bf(v.w) };
    *(ushort4*)(dst + (size_t)i*4) = o;
  }
}

// ---------------- front: visit embedding bags + weight/age linears ----------------
// grid (768,5) block 128. y<3: vis_org[y][row][d]; y>=3: hin2T slots 5,6.
__global__ __launch_bounds__(128) void k_front(const int* __restrict__ vids,
                                               const float* __restrict__ embv,
                                               const float* __restrict__ wv, const float* __restrict__ av,
                                               const float* __restrict__ ww, const float* __restrict__ wb,
                                               const float* __restrict__ aw, const float* __restrict__ ab,
                                               u16* __restrict__ vis_org, u16* __restrict__ hin2T){
  __shared__ int ids[48];
  int y = blockIdx.y, row = blockIdx.x, d = threadIdx.x;
  if (y < 3){
    if (d < 48) ids[d] = vids[((size_t)y*768 + row)*48 + d];
    __syncthreads();
    const float* eb = embv + (size_t)y*2000*128;
    float acc = 0.f;
    #pragma unroll 4
    for (int c = 0; c < 48; ++c){ int id = ids[c]; if (id) acc += eb[(size_t)id*128 + d]; }
    vis_org[((size_t)y*768 + row)*128 + d] = f2bf(acc);
  } else {
    int sidx = y - 3;
    const float* vals = sidx ? av : wv;
    const float* wgt  = sidx ? aw : ww;
    const float* bias = sidx ? ab : wb;
    float v = vals[row];
    float h = (v != 0.f) ? (v * wgt[d] + bias[d]) : 0.f;
    int b = row >> 4, vv = row & 15;
    hin2T[((size_t)(5+sidx)*768 + (size_t)vv*48 + b)*128 + d] = f2bf(h);
  }
}

// ---------------- monitor embedding bag ----------------
// grid (3072,2), block 256: 8 rows/block, 32 lanes/row, 4 d/lane.
// mon_xT[p][m*768+bv][d] = sum_cm e1[id1][d]*e2[id2][d]  (bf16 tables)
__global__ __launch_bounds__(256) void k_embed_mon(const int* __restrict__ mids,
                                                   const u16* __restrict__ embm_b,
                                                   u16* __restrict__ mon_xT){
  int p = blockIdx.y;
  int rid = threadIdx.x >> 5, lane32 = threadIdx.x & 31, d0 = lane32*4;
  __shared__ int ids[8][16];
  if (threadIdx.x < 128){
    int rr = threadIdx.x >> 4, c = threadIdx.x & 15;
    int f = 2*p + (c>>3), cm = c & 7;
    ids[rr][c] = mids[((size_t)f*24576 + (size_t)blockIdx.x*8 + rr)*8 + cm];
  }
  __syncthreads();
  const u16* e1 = embm_b + (size_t)(2*p)*1000*128;
  const u16* e2 = embm_b + (size_t)(2*p+1)*1000*128;
  float a0=0.f,a1=0.f,a2=0.f,a3=0.f;
  #pragma unroll
  for (int c = 0; c < 8; ++c){
    int i1 = ids[rid][c], i2 = ids[rid][8+c];
    if (i1 && i2){
      uint2 a = *(const uint2*)(e1 + (size_t)i1*128 + d0);
      uint2 b = *(const uint2*)(e2 + (size_t)i2*128 + d0);
      a0 += bflo(a.x)*bflo(b.x); a1 += bfhi(a.x)*bfhi(b.x);
      a2 += bflo(a.y)*bflo(b.y); a3 += bfhi(a.y)*bfhi(b.y);
    }
  }
  size_t nm = (size_t)blockIdx.x*8 + rid;
  int bv = (int)(nm >> 5), m = (int)(nm & 31);
  ushort4 o = { f2bf(a0), f2bf(a1), f2bf(a2), f2bf(a3) };
  *(ushort4*)(mon_xT + (size_t)p*24576*128 + ((size_t)m*768 + bv)*128 + d0) = o;
}

// ---------------- fused GRU (input projection + recurrence) ----------------
// mode 0: grid (48,5) T=32. s<2: A=mon_xT[s], rstride=768*128. s>=2:
//         A=vis_org[s-2], rstride=0 (broadcast over time). weights mgru[s];
//         out hin2T[slot], slot=0x32140 nibble, store [v=(lq*4+r)*48 + b=g].
// mode 1: grid (3,7) T=16. A=hin2T[s], rstride=48*128; weights vgru[vi],
//         vi=0x6514320 nibble; out h2[s][b=g*16+lq*4+r][128].
#define ALOAD(D, tt) { const u16* p_ = ap + (size_t)(tt)*rstride; \
  D[0]=*(const bf8*)(p_); D[1]=*(const bf8*)(p_+32); D[2]=*(const bf8*)(p_+64); D[3]=*(const bf8*)(p_+96); }

#define STEP(D, tt, FIRST) { \
  f4 g0={biv[0],biv[0],biv[0],biv[0]}; \
  f4 g1={biv[1],biv[1],biv[1],biv[1]}; \
  f4 g2={biv[2],biv[2],biv[2],biv[2]}; \
  g0=mfma16(D[0],wfi[0][0],g0); g0=mfma16(D[1],wfi[0][1],g0); \
  g0=mfma16(D[2],wfi[0][2],g0); g0=mfma16(D[3],wfi[0][3],g0); \
  g1=mfma16(D[0],wfi[1][0],g1); g1=mfma16(D[1],wfi[1][1],g1); \
  g1=mfma16(D[2],wfi[1][2],g1); g1=mfma16(D[3],wfi[1][3],g1); \
  g2=mfma16(D[0],wfi[2][0],g2); g2=mfma16(D[1],wfi[2][1],g2); \
  g2=mfma16(D[2],wfi[2][2],g2); g2=mfma16(D[3],wfi[2][3],g2); \
  { int tl_ = ((tt)+2 < T) ? (tt)+2 : 0; ALOAD(D, tl_); } \
  f4 a0={bhv[0],bhv[0],bhv[0],bhv[0]}; \
  f4 a1={bhv[1],bhv[1],bhv[1],bhv[1]}; \
  f4 a2={bhv[2],bhv[2],bhv[2],bhv[2]}; \
  if (!(FIRST)){ \
    bf8 hf0 = *(const bf8*)&hlds[cur][lr][0*32+lq*8]; \
    bf8 hf1 = *(const bf8*)&hlds[cur][lr][1*32+lq*8]; \
    bf8 hf2 = *(const bf8*)&hlds[cur][lr][2*32+lq*8]; \
    bf8 hf3 = *(const bf8*)&hlds[cur][lr][3*32+lq*8]; \
    a0=mfma16(hf0,wfh[0][0],a0); a0=mfma16(hf1,wfh[0][1],a0); \
    a0=mfma16(hf2,wfh[0][2],a0); a0=mfma16(hf3,wfh[0][3],a0); \
    a1=mfma16(hf0,wfh[1][0],a1); a1=mfma16(hf1,wfh[1][1],a1); \
    a1=mfma16(hf2,wfh[1][2],a1); a1=mfma16(hf3,wfh[1][3],a1); \
    a2=mfma16(hf0,wfh[2][0],a2); a2=mfma16(hf1,wfh[2][1],a2); \
    a2=mfma16(hf2,wfh[2][2],a2); a2=mfma16(hf3,wfh[2][3],a2); \
  } \
  int nxt_ = cur ^ 1; \
  _Pragma("unroll") \
  for (int r = 0; r < 4; ++r){ \
    float rr2 = sigm(g0[r] + a0[r]); \
    float zz  = sigm(g1[r] + a1[r]); \
    float nn  = tanh_f(g2[r] + rr2*a2[r]); \
    float hv  = (1.0f - zz)*nn + zz*hp[r]; hp[r] = hv; \
    hlds[nxt_][lq*4+r][w*16+lr] = f2bf(hv); \
  } \
  __syncthreads(); cur = nxt_; }

__global__ __launch_bounds__(512, 1) void k_gru(int mode,
    const u16* __restrict__ Asrc, const u16* __restrict__ Asrc2,
    const u16* __restrict__ Wih, const float* __restrict__ bih,
    const u16* __restrict__ Whh, const float* __restrict__ bhh,
    u16* __restrict__ hout, int T){
  int s = blockIdx.y, g = blockIdx.x;
  const u16* A; size_t rstride; u16* ho; int widx;
  if (mode == 0){
    if (s < 2){ A = Asrc + (size_t)s*24576*128; rstride = 768*128; }
    else      { A = Asrc2 + (size_t)(s-2)*768*128; rstride = 0; }
    widx = s;
    int slot = (0x32140u >> (4*s)) & 15;
    ho = hout + (size_t)slot*768*128;
  } else {
    A = Asrc + (size_t)s*768*128; rstride = 48*128;
    widx = (0x6514320u >> (4*s)) & 15;
    ho = hout + (size_t)s*48*128;
  }
  const u16* Wi = Wih + (size_t)widx*384*128;
  const u16* Wh = Whh + (size_t)widx*384*128;
  const float* bi = bih + (size_t)widx*384;
  const float* bh = bhh + (size_t)widx*384;

  int w = threadIdx.x >> 6, l = threadIdx.x & 63;
  int lr = l & 15, lq = l >> 4;

  // weight frags: wave w owns gate-col-chunk w*16..+16 of r,z,n (tiles w,8+w,16+w)
  bf8 wfi[3][4], wfh[3][4]; float biv[3], bhv[3];
  #pragma unroll
  for (int j = 0; j < 3; ++j){
    int colb = (w + 8*j)*16;
    const u16* wpi = Wi + (size_t)(colb + lr)*128 + lq*8;
    const u16* wph = Wh + (size_t)(colb + lr)*128 + lq*8;
    #pragma unroll
    for (int kt = 0; kt < 4; ++kt){
      wfi[j][kt] = *(const bf8*)(wpi + kt*32);
      wfh[j][kt] = *(const bf8*)(wph + kt*32);
    }
    biv[j] = bi[colb + lr];
    bhv[j] = bh[colb + lr];
  }

  const u16* ap = A + (size_t)(g*16 + lr)*128 + lq*8;
  bf8 AF0[4], AF1[4];
  ALOAD(AF0, 0); ALOAD(AF1, 1);

  __shared__ u16 hlds[2][16][132];   // 66-dword row stride: conflict-free b128
  float hp[4] = {0.f,0.f,0.f,0.f};
  int cur = 0;

  STEP(AF0, 0, true); STEP(AF1, 1, false);
  for (int t = 2; t < T; t += 2){
    STEP(AF0, t, false); STEP(AF1, t+1, false);
  }

  if (mode == 0){
    #pragma unroll
    for (int r = 0; r < 4; ++r)
      ho[((size_t)(lq*4+r)*48 + g)*128 + w*16 + lr] = f2bf(hp[r]);
  } else {
    #pragma unroll
    for (int r = 0; r < 4; ++r)
      ho[((size_t)(g*16 + lq*4 + r))*128 + w*16 + lr] = f2bf(hp[r]);
  }
}

// ---------------- final projection ----------------
// grid 48, block 256. out[b][o] = relu-concat(slots) @ fc_out_w^T + fc_out_b
__global__ __launch_bounds__(256) void k_final(const u16* __restrict__ h2,
                                               const float* __restrict__ W,
                                               const float* __restrict__ Bias,
                                               float* __restrict__ out){
  int b = blockIdx.x, t = threadIdx.x;
  __shared__ float emb[896];
  for (int i = t; i < 896; i += 256){
    int j = i >> 7, d = i & 127;
    float v = bf2f(h2[((size_t)j*48 + b)*128 + d]);
    if (j >= 1 && j <= 3) v *= 2.0f;   // slots 1..3 appear twice in reference sum
    emb[i] = fmaxf(v, 0.f);
  }
  __syncthreads();
  float acc = Bias[t];
  const float* wp = W + (size_t)t*896;
  for (int i = 0; i < 896; i += 8){
    float4 w0 = *(const float4*)(wp + i);
    float4 w1 = *(const float4*)(wp + i + 4);
    acc += w0.x*emb[i]   + w0.y*emb[i+1] + w0.z*emb[i+2] + w0.w*emb[i+3];
    acc += w1.x*emb[i+4] + w1.y*emb[i+5] + w1.z*emb[i+6] + w1.w*emb[i+7];
  }
  out[(size_t)b*256 + t] = acc;
}

extern "C" void kernel_launch(void* const* d_in, const int* in_sizes, int n_in,
                              void* d_out, int out_size, void* d_ws, size_t ws_size,
                              hipStream_t stream){
  const int*   visit_ids   = (const int*)d_in[0];
  const int*   mon_ids     = (const int*)d_in[1];
  const float* weight_vals = (const float*)d_in[2];
  const float* age_vals    = (const float*)d_in[3];
  const float* emb_visit   = (const float*)d_in[4];
  const float* emb_mon     = (const float*)d_in[5];
  const float* mgru_Wih    = (const float*)d_in[6];
  const float* mgru_Whh    = (const float*)d_in[7];
  const float* mgru_bih    = (const float*)d_in[8];
  const float* mgru_bhh    = (const float*)d_in[9];
  const float* vgru_Wih    = (const float*)d_in[10];
  const float* vgru_Whh    = (const float*)d_in[11];
  const float* vgru_bih    = (const float*)d_in[12];
  const float* vgru_bhh    = (const float*)d_in[13];
  const float* fc_w_w      = (const float*)d_in[14];
  const float* fc_w_b      = (const float*)d_in[15];
  const float* fc_a_w      = (const float*)d_in[16];
  const float* fc_a_b      = (const float*)d_in[17];
  const float* fc_out_w    = (const float*)d_in[18];
  const float* fc_out_b    = (const float*)d_in[19];

  char* ws = (char*)d_ws;
  size_t o = 0;
  u16* mWih_b  = (u16*)(ws+o); o += 5ull*384*128*2;
  u16* mWhh_b  = (u16*)(ws+o); o += 5ull*384*128*2;
  u16* vWih_b  = (u16*)(ws+o); o += 7ull*384*128*2;
  u16* vWhh_b  = (u16*)(ws+o); o += 7ull*384*128*2;
  u16* embm_b  = (u16*)(ws+o); o += 4ull*1000*128*2;
  u16* mon_xT  = (u16*)(ws+o); o += 2ull*24576*128*2;    // [p][m*768+bv][128]
  u16* vis_org = (u16*)(ws+o); o += 3ull*768*128*2;
  u16* hin2T   = (u16*)(ws+o); o += 7ull*768*128*2;      // [slot][v*48+b][128]
  u16* h2      = (u16*)(ws+o); o += 7ull*48*128*2;       // ~17.6 MB total

  k_prep<<<dim3(500,5), 256, 0, stream>>>(mgru_Wih, mgru_Whh, vgru_Wih, vgru_Whh, emb_mon,
                                          mWih_b, mWhh_b, vWih_b, vWhh_b, embm_b);
  k_front<<<dim3(768,5), 128, 0, stream>>>(visit_ids, emb_visit,
                                           weight_vals, age_vals, fc_w_w, fc_w_b, fc_a_w, fc_a_b,
                                           vis_org, hin2T);
  k_embed_mon<<<dim3(3072,2), 256, 0, stream>>>(mon_ids, embm_b, mon_xT);
  // monitor-level fused GRU: 5 streams -> hin2T slots {0,4,1,2,3}
  k_gru<<<dim3(48,5), 512, 0, stream>>>(0, mon_xT, vis_org,
                                        mWih_b, mgru_bih, mWhh_b, mgru_bhh, hin2T, 32);
  // visit-level fused GRU: 7 streams -> h2
  k_gru<<<dim3(3,7), 512, 0, stream>>>(1, hin2T, (const u16*)0,
                                       vWih_b, vgru_bih, vWhh_b, vgru_bhh, h2, 16);
  k_final<<<48, 256, 0, stream>>>(h2, fc_out_w, fc_out_b, (float*)d_out);
}